// Round 2
// baseline (430.202 us; speedup 1.0000x reference)
//
#include <hip/hip_runtime.h>
#include <hip/hip_bf16.h>
#include <stdint.h>

typedef __bf16 bf16;
typedef __bf16 bf16x8 __attribute__((ext_vector_type(8)));
typedef __bf16 bf16x4 __attribute__((ext_vector_type(4)));
typedef float f32x4 __attribute__((ext_vector_type(4)));

#define NH   16
#define SEQ  2048
#define DM   1024
#define HD   64
#define LOG2E 1.44269504088896340736f

// LDS rows are 128 bytes. Swizzle is an involution within a row (key depends
// only on the row index), so global_load_lds sources can be pre-swizzled.
__device__ __forceinline__ int swz(int r, int o) {
  return o ^ ((r & 7) << 4) ^ (((r >> 3) & 1) << 5);
}

__device__ __forceinline__ void gll16(const void* g, void* l) {
  __builtin_amdgcn_global_load_lds(
      (__attribute__((address_space(1))) unsigned int*)(g),
      (__attribute__((address_space(3))) unsigned int*)(l), 16, 0, 0);
}

// ---------------- weight conversion ----------------
// Wq/Wk/Wv: [H][D][hd] fp32 -> Wt[n][d] bf16, n = h*64+e  (B^T layout, K=d)
__global__ __launch_bounds__(256) void conv_w(const float* __restrict__ W,
                                              bf16* __restrict__ Wt) {
  int i = blockIdx.x * 256 + threadIdx.x;   // over 1M
  int n = i >> 10, d = i & 1023;
  int h = n >> 6, e = n & 63;
  Wt[i] = (bf16)W[(h << 16) + (d << 6) + e];
}

// Wo: [K][N] fp32 -> Wt[n][k] bf16
__global__ __launch_bounds__(256) void conv_wo(const float* __restrict__ W,
                                               bf16* __restrict__ Wt) {
  int i = blockIdx.x * 256 + threadIdx.x;   // over 1M
  int n = i >> 10, k = i & 1023;
  Wt[i] = (bf16)W[(k << 10) + n];
}

// ---------------- GEMM: C = A[M=8192][K=1024] * Bt[N=1024][K=1024]^T -------
// AF32: A is fp32 (reg-stage + convert). else A is bf16 (global_load_lds).
// epi 0: bf16 -> C[((b*16+h)*2048+s)*64+e]  (*scale)   [Q/K projection]
// epi 1: bf16 -> C[((b*16+h)*64+e)*2048+s]             [V projection, transposed]
// epi 2: f32  -> C[mr*1024+n]                          [final Wo GEMM]
template <bool AF32>
__global__ __launch_bounds__(256, 2) void gemm_bt(const void* __restrict__ Av,
                                                  const bf16* __restrict__ Bt,
                                                  void* __restrict__ Cv,
                                                  int epi, float scale) {
  __shared__ char sm[32768];
  char* As = sm;
  char* Bs = sm + 16384;
  int tid = threadIdx.x;
  int wid = tid >> 6, lane = tid & 63;
  int g = lane >> 4, cc = lane & 15;
  int wr = wid >> 1, wc = wid & 1;
  int n0 = blockIdx.x << 7;
  int m0 = blockIdx.y << 7;

  f32x4 acc[4][4];
#pragma unroll
  for (int a = 0; a < 4; ++a)
#pragma unroll
    for (int b = 0; b < 4; ++b)
#pragma unroll
      for (int j = 0; j < 4; ++j) acc[a][b][j] = 0.0f;

  for (int kt = 0; kt < 16; ++kt) {
    int k0 = kt << 6;
    // stage B (bf16, async, pre-swizzled source)
#pragma unroll
    for (int it = 0; it < 4; ++it) {
      int L = (it << 12) + (tid << 4);
      int r = L >> 7, o = L & 127;
      int os = swz(r, o);
      gll16(Bt + (size_t)(n0 + r) * 1024 + k0 + (os >> 1),
            Bs + (it << 12) + (wid << 10));
    }
    // stage A
    if constexpr (AF32) {
      const float* A = (const float*)Av;
      int r = tid >> 1, hf = tid & 1;
      const float* src = A + (size_t)(m0 + r) * 1024 + k0 + hf * 32;
      float4 fv[8];
#pragma unroll
      for (int q = 0; q < 8; ++q) fv[q] = ((const float4*)src)[q];
#pragma unroll
      for (int q = 0; q < 4; ++q) {
        float4 a = fv[2 * q], b = fv[2 * q + 1];
        bf16x8 pk;
        pk[0] = (bf16)a.x; pk[1] = (bf16)a.y; pk[2] = (bf16)a.z; pk[3] = (bf16)a.w;
        pk[4] = (bf16)b.x; pk[5] = (bf16)b.y; pk[6] = (bf16)b.z; pk[7] = (bf16)b.w;
        *(bf16x8*)(As + (r << 7) + swz(r, hf * 64 + q * 16)) = pk;
      }
    } else {
      const bf16* A = (const bf16*)Av;
#pragma unroll
      for (int it = 0; it < 4; ++it) {
        int L = (it << 12) + (tid << 4);
        int r = L >> 7, o = L & 127;
        int os = swz(r, o);
        gll16(A + (size_t)(m0 + r) * 1024 + k0 + (os >> 1),
              As + (it << 12) + (wid << 10));
      }
    }
    __syncthreads();
#pragma unroll
    for (int kk = 0; kk < 2; ++kk) {
      bf16x8 af[4], bfr[4];
#pragma unroll
      for (int fm = 0; fm < 4; ++fm) {
        int r = (wr << 6) + (fm << 4) + cc;
        af[fm] = *(const bf16x8*)(As + (r << 7) + swz(r, (kk << 6) + (g << 4)));
      }
#pragma unroll
      for (int fn = 0; fn < 4; ++fn) {
        int r = (wc << 6) + (fn << 4) + cc;
        bfr[fn] = *(const bf16x8*)(Bs + (r << 7) + swz(r, (kk << 6) + (g << 4)));
      }
#pragma unroll
      for (int fm = 0; fm < 4; ++fm)
#pragma unroll
        for (int fn = 0; fn < 4; ++fn)
          acc[fm][fn] = __builtin_amdgcn_mfma_f32_16x16x32_bf16(
              af[fm], bfr[fn], acc[fm][fn], 0, 0, 0);
    }
    __syncthreads();
  }

  // epilogue
#pragma unroll
  for (int fm = 0; fm < 4; ++fm) {
#pragma unroll
    for (int fn = 0; fn < 4; ++fn) {
      f32x4 v = acc[fm][fn];
      int mr = m0 + (wr << 6) + (fm << 4) + (g << 2);
      int n = n0 + (wc << 6) + (fn << 4) + cc;
      if (epi == 2) {
        float* C = (float*)Cv;
#pragma unroll
        for (int j = 0; j < 4; ++j) C[(size_t)(mr + j) * 1024 + n] = v[j];
      } else if (epi == 0) {
        bf16* C = (bf16*)Cv;
        int h = n >> 6, e = n & 63;
#pragma unroll
        for (int j = 0; j < 4; ++j) {
          int b = (mr + j) >> 11, s = (mr + j) & 2047;
          C[((size_t)(b * NH + h) * SEQ + s) * HD + e] = (bf16)(v[j] * scale);
        }
      } else {  // epi == 1 : V transposed
        bf16* C = (bf16*)Cv;
        int h = n >> 6, e = n & 63;
        int b = mr >> 11, s = mr & 2047;
        bf16x4 t;
#pragma unroll
        for (int j = 0; j < 4; ++j) t[j] = (bf16)(v[j] * scale);
        *(bf16x4*)(C + ((size_t)(b * NH + h) * HD + e) * SEQ + s) = t;
      }
    }
  }
}

// ---------------- flash attention (causal) ----------------
// Qh,Kh: [BH][S][64] bf16 (Q pre-scaled by 1/8). Vt: [BH][64][S] bf16.
// Oa: [BH][S][64] bf16. Block: 4 waves x 32 q-rows = 128 q-rows. KVBLK=64.
__global__ __launch_bounds__(256, 2) void attn_fwd(const bf16* __restrict__ Qh,
                                                   const bf16* __restrict__ Kh,
                                                   const bf16* __restrict__ Vt,
                                                   bf16* __restrict__ Oa) {
  __shared__ char sm[32768];  // Ks 8K | Vs 8K | Ps 16K (4K per wave)
  char* Ks = sm;
  char* Vs = sm + 8192;
  char* Ps = sm + 16384;
  int tid = threadIdx.x, wid = tid >> 6, lane = tid & 63;
  int g = lane >> 4, cc = lane & 15;
  int qx = (int)(gridDim.x - 1 - blockIdx.x);  // heavy tiles first
  int bh = blockIdx.y;
  int q0 = qx << 7;
  int sb = q0 + (wid << 5);  // this wave's first q-row
  const bf16* Qp = Qh + ((size_t)bh * SEQ + sb) * HD;

  bf16x8 qf[2][2];
#pragma unroll
  for (int fm = 0; fm < 2; ++fm)
#pragma unroll
    for (int kk = 0; kk < 2; ++kk)
      qf[fm][kk] = *(const bf16x8*)(Qp + ((fm << 4) + cc) * HD + (kk << 5) + (g << 3));

  f32x4 acc[2][4];
  float mst[2][4], lst[2][4];
#pragma unroll
  for (int fm = 0; fm < 2; ++fm) {
#pragma unroll
    for (int fn = 0; fn < 4; ++fn)
#pragma unroll
      for (int j = 0; j < 4; ++j) acc[fm][fn][j] = 0.0f;
#pragma unroll
    for (int j = 0; j < 4; ++j) { mst[fm][j] = -1e30f; lst[fm][j] = 0.0f; }
  }

  int nkv = (qx << 1) + 2;
  for (int kv = 0; kv < nkv; ++kv) {
    int t0 = kv << 6;
#pragma unroll
    for (int it = 0; it < 2; ++it) {
      int L = (it << 12) + (tid << 4);
      int r = L >> 7, o = L & 127;
      int os = swz(r, o);
      gll16(Kh + ((size_t)bh * SEQ + t0 + r) * HD + (os >> 1),
            Ks + (it << 12) + (wid << 10));
      gll16(Vt + ((size_t)bh * HD + r) * SEQ + t0 + (os >> 1),
            Vs + (it << 12) + (wid << 10));
    }
    __syncthreads();
    if (t0 <= sb + 31) {  // wave has unmasked work in this tile
      f32x4 sc[2][4];
#pragma unroll
      for (int fm = 0; fm < 2; ++fm)
#pragma unroll
        for (int fn = 0; fn < 4; ++fn)
#pragma unroll
          for (int j = 0; j < 4; ++j) sc[fm][fn][j] = 0.0f;
      // S = Q K^T
#pragma unroll
      for (int kk = 0; kk < 2; ++kk) {
        bf16x8 kb[4];
#pragma unroll
        for (int fn = 0; fn < 4; ++fn) {
          int r = (fn << 4) + cc;
          kb[fn] = *(const bf16x8*)(Ks + (r << 7) + swz(r, (kk << 6) + (g << 4)));
        }
#pragma unroll
        for (int fm = 0; fm < 2; ++fm)
#pragma unroll
          for (int fn = 0; fn < 4; ++fn)
            sc[fm][fn] = __builtin_amdgcn_mfma_f32_16x16x32_bf16(
                qf[fm][kk], kb[fn], sc[fm][fn], 0, 0, 0);
      }
      // causal mask on diagonal tiles
      if (t0 + 63 > sb) {
#pragma unroll
        for (int fm = 0; fm < 2; ++fm)
#pragma unroll
          for (int fn = 0; fn < 4; ++fn)
#pragma unroll
            for (int j = 0; j < 4; ++j) {
              int s = sb + (fm << 4) + (g << 2) + j;
              int t = t0 + (fn << 4) + cc;
              if (t > s) sc[fm][fn][j] = -1e30f;
            }
      }
      // online softmax
#pragma unroll
      for (int fm = 0; fm < 2; ++fm) {
        float mnew[4], scl[4], rsum[4];
#pragma unroll
        for (int j = 0; j < 4; ++j) {
          float rm = fmaxf(fmaxf(sc[fm][0][j], sc[fm][1][j]),
                           fmaxf(sc[fm][2][j], sc[fm][3][j]));
          rm = fmaxf(rm, __shfl_xor(rm, 1, 64));
          rm = fmaxf(rm, __shfl_xor(rm, 2, 64));
          rm = fmaxf(rm, __shfl_xor(rm, 4, 64));
          rm = fmaxf(rm, __shfl_xor(rm, 8, 64));
          float mo = mst[fm][j];
          mnew[j] = fmaxf(mo, rm);
          scl[j] = exp2f((mo - mnew[j]) * LOG2E);
          rsum[j] = 0.0f;
        }
#pragma unroll
        for (int fn = 0; fn < 4; ++fn)
#pragma unroll
          for (int j = 0; j < 4; ++j) {
            float p = exp2f((sc[fm][fn][j] - mnew[j]) * LOG2E);
            rsum[j] += p;
            int rp = (fm << 4) + (g << 2) + j;
            *(bf16*)(Ps + (wid << 12) + (rp << 7) +
                     swz(rp, ((fn << 4) + cc) << 1)) = (bf16)p;
          }
#pragma unroll
        for (int j = 0; j < 4; ++j) {
          rsum[j] += __shfl_xor(rsum[j], 1, 64);
          rsum[j] += __shfl_xor(rsum[j], 2, 64);
          rsum[j] += __shfl_xor(rsum[j], 4, 64);
          rsum[j] += __shfl_xor(rsum[j], 8, 64);
          lst[fm][j] = lst[fm][j] * scl[j] + rsum[j];
          mst[fm][j] = mnew[j];
        }
#pragma unroll
        for (int fn = 0; fn < 4; ++fn)
#pragma unroll
          for (int j = 0; j < 4; ++j) acc[fm][fn][j] *= scl[j];
      }
      // O += P V   (A = P from wave-private LDS, B = V^T tile)
#pragma unroll
      for (int ks = 0; ks < 2; ++ks) {
        bf16x8 pa[2], vb[4];
#pragma unroll
        for (int fm = 0; fm < 2; ++fm) {
          int r = (fm << 4) + cc;
          pa[fm] = *(const bf16x8*)(Ps + (wid << 12) + (r << 7) +
                                    swz(r, (ks << 6) + (g << 4)));
        }
#pragma unroll
        for (int fn = 0; fn < 4; ++fn) {
          int r = (fn << 4) + cc;
          vb[fn] = *(const bf16x8*)(Vs + (r << 7) + swz(r, (ks << 6) + (g << 4)));
        }
#pragma unroll
        for (int fm = 0; fm < 2; ++fm)
#pragma unroll
          for (int fn = 0; fn < 4; ++fn)
            acc[fm][fn] = __builtin_amdgcn_mfma_f32_16x16x32_bf16(
                pa[fm], vb[fn], acc[fm][fn], 0, 0, 0);
      }
    }
    __syncthreads();
  }
  // epilogue: O = acc / l
#pragma unroll
  for (int fm = 0; fm < 2; ++fm) {
#pragma unroll
    for (int j = 0; j < 4; ++j) {
      float inv = 1.0f / lst[fm][j];
      int s = sb + (fm << 4) + (g << 2) + j;
#pragma unroll
      for (int fn = 0; fn < 4; ++fn)
        Oa[((size_t)bh * SEQ + s) * HD + (fn << 4) + cc] =
            (bf16)(acc[fm][fn][j] * inv);
    }
  }
}

// ---------------- launch ----------------
extern "C" void kernel_launch(void* const* d_in, const int* in_sizes, int n_in,
                              void* d_out, int out_size, void* d_ws,
                              size_t ws_size, hipStream_t stream) {
  const float* q = (const float*)d_in[0];
  const float* k = (const float*)d_in[1];
  const float* v = (const float*)d_in[2];
  const float* Wq = (const float*)d_in[3];
  const float* Wk = (const float*)d_in[4];
  const float* Wv = (const float*)d_in[5];
  const float* Wo = (const float*)d_in[6];
  char* ws = (char*)d_ws;

  const size_t MB = 1024 * 1024;
  bf16* WqT = (bf16*)(ws + 0 * MB);
  bf16* WkT = (bf16*)(ws + 2 * MB);
  bf16* WvT = (bf16*)(ws + 4 * MB);
  bf16* WoT = (bf16*)(ws + 6 * MB);
  bf16* Qh  = (bf16*)(ws + 8 * MB);
  bf16* Kh  = (bf16*)(ws + 24 * MB);
  bf16* Vt  = (bf16*)(ws + 40 * MB);
  bf16* Att = (bf16*)(ws + 56 * MB);   // total 72 MiB

  conv_w<<<4096, 256, 0, stream>>>(Wq, WqT);
  conv_w<<<4096, 256, 0, stream>>>(Wk, WkT);
  conv_w<<<4096, 256, 0, stream>>>(Wv, WvT);
  conv_wo<<<4096, 256, 0, stream>>>(Wo, WoT);

  dim3 gg(8, 64);
  gemm_bt<true><<<gg, 256, 0, stream>>>(q, WqT, Qh, 0, 0.125f);
  gemm_bt<true><<<gg, 256, 0, stream>>>(k, WkT, Kh, 0, 1.0f);
  gemm_bt<true><<<gg, 256, 0, stream>>>(v, WvT, Vt, 1, 1.0f);

  attn_fwd<<<dim3(16, 64), 256, 0, stream>>>(Qh, Kh, Vt, Att);

  gemm_bt<false><<<gg, 256, 0, stream>>>(Att, WoT, (float*)d_out, 2, 1.0f);
}

// Round 4
// 284.209 us; speedup vs baseline: 1.5137x; 1.5137x over previous
//
#include <hip/hip_runtime.h>
#include <hip/hip_bf16.h>
#include <stdint.h>

typedef __bf16 bf16;
typedef __bf16 bf16x8 __attribute__((ext_vector_type(8)));
typedef __bf16 bf16x4 __attribute__((ext_vector_type(4)));
typedef __bf16 bf16x2 __attribute__((ext_vector_type(2)));
typedef float f32x4 __attribute__((ext_vector_type(4)));
typedef float f32x16 __attribute__((ext_vector_type(16)));
typedef int i32x4 __attribute__((ext_vector_type(4)));

#define NH   16
#define SEQ  2048
#define DM   1024
#define HD   64
#define THRD 11.0f   // defer-max threshold, log2 domain (~e^7.6)

// LDS rows are 128 bytes. Swizzle is an involution within a row (key depends
// only on the row index), so global_load_lds sources can be pre-swizzled.
__device__ __forceinline__ int swz(int r, int o) {
  return o ^ ((r & 7) << 4) ^ (((r >> 3) & 1) << 5);
}

__device__ __forceinline__ void gll16(const void* g, void* l) {
  __builtin_amdgcn_global_load_lds(
      (__attribute__((address_space(1))) unsigned int*)(g),
      (__attribute__((address_space(3))) unsigned int*)(l), 16, 0, 0);
}

__device__ __forceinline__ int pk2(float a, float b) {
  bf16x2 t; t[0] = (bf16)a; t[1] = (bf16)b;
  return __builtin_bit_cast(int, t);
}

// ---------------- weight conversion ----------------
__global__ __launch_bounds__(256) void conv_w(const float* __restrict__ W,
                                              bf16* __restrict__ Wt) {
  int i = blockIdx.x * 256 + threadIdx.x;
  int n = i >> 10, d = i & 1023;
  int h = n >> 6, e = n & 63;
  Wt[i] = (bf16)W[(h << 16) + (d << 6) + e];
}

__global__ __launch_bounds__(256) void conv_wo(const float* __restrict__ W,
                                               bf16* __restrict__ Wt) {
  int i = blockIdx.x * 256 + threadIdx.x;
  int n = i >> 10, k = i & 1023;
  Wt[i] = (bf16)W[(k << 10) + n];
}

// ---------------- GEMM: C = A[8192][1024] * Bt[1024][1024]^T ----------------
template <bool AF32>
__global__ __launch_bounds__(256, 2) void gemm_bt(const void* __restrict__ Av,
                                                  const bf16* __restrict__ Bt,
                                                  void* __restrict__ Cv,
                                                  int epi, float scale) {
  __shared__ char sm[32768];
  char* As = sm;
  char* Bs = sm + 16384;
  int tid = threadIdx.x;
  int wid = tid >> 6, lane = tid & 63;
  int g = lane >> 4, cc = lane & 15;
  int wr = wid >> 1, wc = wid & 1;
  int n0 = blockIdx.x << 7;
  int m0 = blockIdx.y << 7;

  f32x4 acc[4][4];
#pragma unroll
  for (int a = 0; a < 4; ++a)
#pragma unroll
    for (int b = 0; b < 4; ++b)
#pragma unroll
      for (int j = 0; j < 4; ++j) acc[a][b][j] = 0.0f;

  for (int kt = 0; kt < 16; ++kt) {
    int k0 = kt << 6;
#pragma unroll
    for (int it = 0; it < 4; ++it) {
      int L = (it << 12) + (tid << 4);
      int r = L >> 7, o = L & 127;
      int os = swz(r, o);
      gll16(Bt + (size_t)(n0 + r) * 1024 + k0 + (os >> 1),
            Bs + (it << 12) + (wid << 10));
    }
    if constexpr (AF32) {
      const float* A = (const float*)Av;
      int r = tid >> 1, hf = tid & 1;
      const float* src = A + (size_t)(m0 + r) * 1024 + k0 + hf * 32;
      float4 fv[8];
#pragma unroll
      for (int q = 0; q < 8; ++q) fv[q] = ((const float4*)src)[q];
#pragma unroll
      for (int q = 0; q < 4; ++q) {
        float4 a = fv[2 * q], b = fv[2 * q + 1];
        bf16x8 pk;
        pk[0] = (bf16)a.x; pk[1] = (bf16)a.y; pk[2] = (bf16)a.z; pk[3] = (bf16)a.w;
        pk[4] = (bf16)b.x; pk[5] = (bf16)b.y; pk[6] = (bf16)b.z; pk[7] = (bf16)b.w;
        *(bf16x8*)(As + (r << 7) + swz(r, hf * 64 + q * 16)) = pk;
      }
    } else {
      const bf16* A = (const bf16*)Av;
#pragma unroll
      for (int it = 0; it < 4; ++it) {
        int L = (it << 12) + (tid << 4);
        int r = L >> 7, o = L & 127;
        int os = swz(r, o);
        gll16(A + (size_t)(m0 + r) * 1024 + k0 + (os >> 1),
              As + (it << 12) + (wid << 10));
      }
    }
    __syncthreads();
#pragma unroll
    for (int kk = 0; kk < 2; ++kk) {
      bf16x8 af[4], bfr[4];
#pragma unroll
      for (int fm = 0; fm < 4; ++fm) {
        int r = (wr << 6) + (fm << 4) + cc;
        af[fm] = *(const bf16x8*)(As + (r << 7) + swz(r, (kk << 6) + (g << 4)));
      }
#pragma unroll
      for (int fn = 0; fn < 4; ++fn) {
        int r = (wc << 6) + (fn << 4) + cc;
        bfr[fn] = *(const bf16x8*)(Bs + (r << 7) + swz(r, (kk << 6) + (g << 4)));
      }
#pragma unroll
      for (int fm = 0; fm < 4; ++fm)
#pragma unroll
        for (int fn = 0; fn < 4; ++fn)
          acc[fm][fn] = __builtin_amdgcn_mfma_f32_16x16x32_bf16(
              af[fm], bfr[fn], acc[fm][fn], 0, 0, 0);
    }
    __syncthreads();
  }

#pragma unroll
  for (int fm = 0; fm < 4; ++fm) {
#pragma unroll
    for (int fn = 0; fn < 4; ++fn) {
      f32x4 v = acc[fm][fn];
      int mr = m0 + (wr << 6) + (fm << 4) + (g << 2);
      int n = n0 + (wc << 6) + (fn << 4) + cc;
      if (epi == 2) {
        float* C = (float*)Cv;
#pragma unroll
        for (int j = 0; j < 4; ++j) C[(size_t)(mr + j) * 1024 + n] = v[j];
      } else if (epi == 0) {
        bf16* C = (bf16*)Cv;
        int h = n >> 6, e = n & 63;
#pragma unroll
        for (int j = 0; j < 4; ++j) {
          int b = (mr + j) >> 11, s = (mr + j) & 2047;
          C[((size_t)(b * NH + h) * SEQ + s) * HD + e] = (bf16)(v[j] * scale);
        }
      } else {
        bf16* C = (bf16*)Cv;
        int h = n >> 6, e = n & 63;
        int b = mr >> 11, s = mr & 2047;
        bf16x4 t;
#pragma unroll
        for (int j = 0; j < 4; ++j) t[j] = (bf16)(v[j] * scale);
        *(bf16x4*)(C + ((size_t)(b * NH + h) * HD + e) * SEQ + s) = t;
      }
    }
  }
}

// ---------------- flash attention v2 (swapped-QK, in-register softmax) ------
// Qh: [BH][S][64] bf16, pre-scaled by 0.125*log2(e). Kh: [BH][S][64].
// Vt: [BH][64][S]. Oa: [BH][S][64].
// Block: 4 waves x 32 q-rows; two paired q-tiles (qx, 15-qx) -> uniform work.
// KVBLK=64, double-buffered K/V staging, one vmcnt(0)+barrier per tile.
// All cross-lane exchanges via __shfl_xor (unambiguous semantics).
__global__ __launch_bounds__(256, 3) void attn_fwd(const bf16* __restrict__ Qh,
                                                   const bf16* __restrict__ Kh,
                                                   const bf16* __restrict__ Vt,
                                                   bf16* __restrict__ Oa) {
  __shared__ char sm[32768];  // [K0 8K | V0 8K | K1 8K | V1 8K]
  int tid = threadIdx.x, wid = tid >> 6;
  int lane = tid & 63, cc = lane & 31, hi = lane >> 5;
  int h4 = hi << 2;
  int qp = blockIdx.x, bh = blockIdx.y;
  const bf16* Kb = Kh + (size_t)bh * SEQ * HD;
  const bf16* Vb = Vt + (size_t)bh * HD * SEQ;

  for (int ph = 0; ph < 2; ++ph) {
    int qx = ph ? (15 - qp) : qp;
    int q0 = qx << 7;
    int sb = q0 + (wid << 5);

    // Q fragments: B-operand col = q-row s = sb+cc, k = kk*16 + hi*8 + 0..7
    const bf16* Qp = Qh + ((size_t)bh * SEQ + sb + cc) * HD + (hi << 3);
    bf16x8 qf[4];
#pragma unroll
    for (int kk = 0; kk < 4; ++kk) qf[kk] = *(const bf16x8*)(Qp + (kk << 4));

    f32x16 acc[2];
#pragma unroll
    for (int eb = 0; eb < 2; ++eb)
#pragma unroll
      for (int r = 0; r < 16; ++r) acc[eb][r] = 0.f;
    float m = -3e38f, l = 0.f;

    int nkv = (qx << 1) + 2;
    int cur = 0;
    // prologue: stage tile 0 into buffer 0
#pragma unroll
    for (int i2 = 0; i2 < 2; ++i2) {
      int L = (i2 << 12) + (tid << 4);
      int r = L >> 7, o = L & 127;
      int os = swz(r, o);
      gll16(Kb + (size_t)r * HD + (os >> 1), sm + (i2 << 12) + (wid << 10));
      gll16(Vb + (size_t)r * SEQ + (os >> 1), sm + 8192 + (i2 << 12) + (wid << 10));
    }
    asm volatile("s_waitcnt vmcnt(0)" ::: "memory");
    __builtin_amdgcn_s_barrier();
    __builtin_amdgcn_sched_barrier(0);

    for (int it = 0; it < nkv; ++it) {
      int t0 = it << 6;
      char* Ks = sm + (cur << 14);
      char* Vs = Ks + 8192;
      // prefetch next tile into other buffer (flies during compute)
      if (it + 1 < nkv) {
        char* nb = sm + ((cur ^ 1) << 14);
        int t1 = t0 + 64;
#pragma unroll
        for (int i2 = 0; i2 < 2; ++i2) {
          int L = (i2 << 12) + (tid << 4);
          int r = L >> 7, o = L & 127;
          int os = swz(r, o);
          gll16(Kb + (size_t)(t1 + r) * HD + (os >> 1),
                nb + (i2 << 12) + (wid << 10));
          gll16(Vb + (size_t)r * SEQ + t1 + (os >> 1),
                nb + 8192 + (i2 << 12) + (wid << 10));
        }
      }
      if (t0 <= sb + 31) {
        // S^T = K Q^T : D[t][s], col s = lane&31, row t = tb*32 + crow(r,hi)
        f32x16 sc[2];
#pragma unroll
        for (int tb = 0; tb < 2; ++tb) {
#pragma unroll
          for (int r = 0; r < 16; ++r) sc[tb][r] = 0.f;
#pragma unroll
          for (int kk = 0; kk < 4; ++kk) {
            int rr = (tb << 5) + cc;
            bf16x8 kf = *(const bf16x8*)(Ks + (rr << 7) +
                                         swz(rr, (kk << 5) + (hi << 4)));
            sc[tb] = __builtin_amdgcn_mfma_f32_32x32x16_bf16(kf, qf[kk],
                                                             sc[tb], 0, 0, 0);
          }
        }
        // causal mask (diag tiles only)
        if (t0 + 63 > sb) {
          int s = sb + cc;
#pragma unroll
          for (int tb = 0; tb < 2; ++tb)
#pragma unroll
            for (int r = 0; r < 16; ++r) {
              int t = t0 + (tb << 5) + (r & 3) + ((r >> 2) << 3) + h4;
              if (t > s) sc[tb][r] = -3e38f;
            }
        }
        // row max: full P-row for q-row s=cc lives in lanes {cc, cc+32}
        float pm = sc[0][0];
#pragma unroll
        for (int r = 1; r < 16; ++r) pm = fmaxf(pm, sc[0][r]);
#pragma unroll
        for (int r = 0; r < 16; ++r) pm = fmaxf(pm, sc[1][r]);
        pm = fmaxf(pm, __shfl_xor(pm, 32, 64));
        // defer-max: rescale only when max grew past threshold
        if (!__all(pm - m <= THRD)) {
          float mn = fmaxf(m, pm);
          float sclf = exp2f(m - mn);
          m = mn; l *= sclf;
          int sclb = __builtin_bit_cast(int, sclf);
#pragma unroll
          for (int r = 0; r < 16; ++r) {
            int ssel = (r & 3) + ((r >> 2) << 3) + h4;
            float sr = __builtin_bit_cast(
                float, __builtin_amdgcn_ds_bpermute(ssel << 2, sclb));
            acc[0][r] *= sr;
            acc[1][r] *= sr;
          }
        }
        // P = exp2(sc - m); row sum
        float rs = 0.f;
#pragma unroll
        for (int tb = 0; tb < 2; ++tb)
#pragma unroll
          for (int r = 0; r < 16; ++r) {
            float p = exp2f(sc[tb][r] - m);
            sc[tb][r] = p;
            rs += p;
          }
        l += rs + __shfl_xor(rs, 32, 64);
        // O += P V : build PV A-frags.
        // Lane holds u = (r&3) + 4*hi + 8*(r>>2) within each 16-k chunk;
        // A-frag needs u = 8*hi + j. Cross-half exchange via shfl_xor(32):
        //   hi=0 words: [w00, w01, partner w00, partner w01]
        //   hi=1 words: [partner w10, partner w11, w10, w11]
#pragma unroll
        for (int ks = 0; ks < 4; ++ks) {
          int tb = ks >> 1, base = (ks & 1) << 3;
          int w00 = pk2(sc[tb][base + 0], sc[tb][base + 1]);
          int w01 = pk2(sc[tb][base + 2], sc[tb][base + 3]);
          int w10 = pk2(sc[tb][base + 4], sc[tb][base + 5]);
          int w11 = pk2(sc[tb][base + 6], sc[tb][base + 7]);
          int selB0 = hi ? w00 : w10;
          int selB1 = hi ? w01 : w11;
          int cross0 = __shfl_xor(selB0, 32, 64);
          int cross1 = __shfl_xor(selB1, 32, 64);
          i32x4 wv;
          wv[0] = hi ? cross0 : w00;
          wv[1] = hi ? cross1 : w01;
          wv[2] = hi ? w10 : cross0;
          wv[3] = hi ? w11 : cross1;
          bf16x8 pa = __builtin_bit_cast(bf16x8, wv);
#pragma unroll
          for (int eb = 0; eb < 2; ++eb) {
            int rr = (eb << 5) + cc;
            bf16x8 vf = *(const bf16x8*)(Vs + (rr << 7) +
                                         swz(rr, (ks << 5) + (hi << 4)));
            acc[eb] = __builtin_amdgcn_mfma_f32_32x32x16_bf16(pa, vf,
                                                              acc[eb], 0, 0, 0);
          }
        }
      }
      asm volatile("s_waitcnt vmcnt(0)" ::: "memory");
      __builtin_amdgcn_s_barrier();
      __builtin_amdgcn_sched_barrier(0);
      cur ^= 1;
    }
    // epilogue: O = acc / l
    float invl = 1.0f / l;
    int ilb = __builtin_bit_cast(int, invl);
    bf16* Op = Oa + ((size_t)bh * SEQ + sb) * HD;
#pragma unroll
    for (int r = 0; r < 16; ++r) {
      int ssel = (r & 3) + ((r >> 2) << 3) + h4;
      float ir = __builtin_bit_cast(
          float, __builtin_amdgcn_ds_bpermute(ssel << 2, ilb));
#pragma unroll
      for (int eb = 0; eb < 2; ++eb)
        Op[(size_t)ssel * HD + (eb << 5) + cc] = (bf16)(acc[eb][r] * ir);
    }
  }
}

// ---------------- launch ----------------
extern "C" void kernel_launch(void* const* d_in, const int* in_sizes, int n_in,
                              void* d_out, int out_size, void* d_ws,
                              size_t ws_size, hipStream_t stream) {
  const float* q = (const float*)d_in[0];
  const float* k = (const float*)d_in[1];
  const float* v = (const float*)d_in[2];
  const float* Wq = (const float*)d_in[3];
  const float* Wk = (const float*)d_in[4];
  const float* Wv = (const float*)d_in[5];
  const float* Wo = (const float*)d_in[6];
  char* ws = (char*)d_ws;

  const size_t MB = 1024 * 1024;
  bf16* WqT = (bf16*)(ws + 0 * MB);
  bf16* WkT = (bf16*)(ws + 2 * MB);
  bf16* WvT = (bf16*)(ws + 4 * MB);
  bf16* WoT = (bf16*)(ws + 6 * MB);
  bf16* Qh  = (bf16*)(ws + 8 * MB);
  bf16* Kh  = (bf16*)(ws + 24 * MB);
  bf16* Vt  = (bf16*)(ws + 40 * MB);
  bf16* Att = (bf16*)(ws + 56 * MB);

  conv_w<<<4096, 256, 0, stream>>>(Wq, WqT);
  conv_w<<<4096, 256, 0, stream>>>(Wk, WkT);
  conv_w<<<4096, 256, 0, stream>>>(Wv, WvT);
  conv_wo<<<4096, 256, 0, stream>>>(Wo, WoT);

  dim3 gg(8, 64);
  // Q pre-scale folds 1/sqrt(64) and log2(e) so softmax uses exp2 directly.
  gemm_bt<true><<<gg, 256, 0, stream>>>(q, WqT, Qh, 0, 0.125f * 1.44269504f);
  gemm_bt<true><<<gg, 256, 0, stream>>>(k, WkT, Kh, 0, 1.0f);
  gemm_bt<true><<<gg, 256, 0, stream>>>(v, WvT, Vt, 1, 1.0f);

  attn_fwd<<<dim3(8, 64), 256, 0, stream>>>(Qh, Kh, Vt, Att);

  gemm_bt<false><<<gg, 256, 0, stream>>>(Att, WoT, (float*)d_out, 2, 1.0f);
}

// Round 5
// 251.901 us; speedup vs baseline: 1.7078x; 1.1283x over previous
//
#include <hip/hip_runtime.h>
#include <hip/hip_bf16.h>
#include <stdint.h>

typedef __bf16 bf16;
typedef __bf16 bf16x8 __attribute__((ext_vector_type(8)));
typedef __bf16 bf16x4 __attribute__((ext_vector_type(4)));
typedef __bf16 bf16x2 __attribute__((ext_vector_type(2)));
typedef float f32x4 __attribute__((ext_vector_type(4)));
typedef float f32x16 __attribute__((ext_vector_type(16)));
typedef int i32x4 __attribute__((ext_vector_type(4)));

#define NH   16
#define SEQ  2048
#define DM   1024
#define HD   64
#define THRD 11.0f   // defer-max threshold, log2 domain

// LDS rows are 128 bytes. Swizzle is an involution within a row.
__device__ __forceinline__ int swz(int r, int o) {
  return o ^ ((r & 7) << 4) ^ (((r >> 3) & 1) << 5);
}

__device__ __forceinline__ void gll16(const void* g, void* l) {
  __builtin_amdgcn_global_load_lds(
      (__attribute__((address_space(1))) unsigned int*)(g),
      (__attribute__((address_space(3))) unsigned int*)(l), 16, 0, 0);
}

__device__ __forceinline__ int pk2(float a, float b) {
  bf16x2 t; t[0] = (bf16)a; t[1] = (bf16)b;
  return __builtin_bit_cast(int, t);
}

// ---------------- fused weight transpose-convert ----------------
// z<3:  Wt[h*64+e][d] = (bf16)W[h][d][e]   (grid.y = h, grid.x = d-chunk)
// z==3: Wt[n][k]      = (bf16)Wo[k][n]     (grid.y = n-chunk, grid.x = k-chunk)
// 64x64 LDS tile; coalesced read and write.
__global__ __launch_bounds__(256) void conv_wt(const float* __restrict__ Wq,
                                               const float* __restrict__ Wk,
                                               const float* __restrict__ Wv,
                                               const float* __restrict__ Wo,
                                               bf16* __restrict__ WqT,
                                               bf16* __restrict__ WkT,
                                               bf16* __restrict__ WvT,
                                               bf16* __restrict__ WoT) {
  __shared__ float tile[64][65];
  int z = blockIdx.z, t = threadIdx.x;
  int d0 = blockIdx.x << 6;
  if (z < 3) {
    const float* W = (z == 0 ? Wq : z == 1 ? Wk : Wv) + ((size_t)blockIdx.y << 16);
#pragma unroll
    for (int i = 0; i < 4; ++i) {
      int slot = (i << 8) + t;           // 0..1023
      int r = slot >> 4, c4 = (slot & 15) << 2;
      float4 fv = *(const float4*)(W + (size_t)(d0 + r) * 64 + c4);
      tile[r][c4] = fv.x; tile[r][c4 + 1] = fv.y;
      tile[r][c4 + 2] = fv.z; tile[r][c4 + 3] = fv.w;
    }
  } else {
    int n0 = blockIdx.y << 6;
#pragma unroll
    for (int i = 0; i < 4; ++i) {
      int slot = (i << 8) + t;
      int r = slot >> 4, c4 = (slot & 15) << 2;
      float4 fv = *(const float4*)(Wo + (size_t)(d0 + r) * 1024 + n0 + c4);
      tile[r][c4] = fv.x; tile[r][c4 + 1] = fv.y;
      tile[r][c4 + 2] = fv.z; tile[r][c4 + 3] = fv.w;
    }
  }
  __syncthreads();
  bf16* Wt = z == 0 ? WqT : z == 1 ? WkT : z == 2 ? WvT : WoT;
  size_t base = (z < 3) ? ((size_t)blockIdx.y << 16)
                        : (size_t)(blockIdx.y << 6) * 1024;
  int e = t >> 2, dq = (t & 3) << 4;
  bf16x8 o0, o1;
#pragma unroll
  for (int j = 0; j < 8; ++j) {
    o0[j] = (bf16)tile[dq + j][e];
    o1[j] = (bf16)tile[dq + 8 + j][e];
  }
  bf16* p = Wt + base + (size_t)e * 1024 + d0 + dq;
  *(bf16x8*)p = o0;
  *(bf16x8*)(p + 8) = o1;
}

// ---------------- input fp32 -> bf16 convert (big-ws path) ----------------
__global__ __launch_bounds__(256) void conv_in(const float* __restrict__ q,
                                               const float* __restrict__ k,
                                               const float* __restrict__ v,
                                               bf16* __restrict__ qb,
                                               bf16* __restrict__ kb,
                                               bf16* __restrict__ vb) {
  int z = blockIdx.y;
  const float* src = z == 0 ? q : z == 1 ? k : v;
  bf16* dst = z == 0 ? qb : z == 1 ? kb : vb;
  int i = (blockIdx.x * 256 + threadIdx.x) << 2;
  float4 f = *(const float4*)(src + i);
  bf16x4 o; o[0] = (bf16)f.x; o[1] = (bf16)f.y; o[2] = (bf16)f.z; o[3] = (bf16)f.w;
  *(bf16x4*)(dst + i) = o;
}

// ---------------- GEMM body: C = A[8192][1024] * Bt[1024][1024]^T -----------
// epi 0: bf16 -> C[((b*16+h)*2048+s)*64+e] (*scale)  [Q/K projection]
// epi 1: bf16 -> C[((b*16+h)*64+e)*2048+s]           [V projection, transposed]
// epi 2: f32  -> C[mr*1024+n]                        [final Wo GEMM]
template <bool AF32>
__device__ __forceinline__ void gemm_body(char* sm, const void* Av,
                                          const bf16* Bt, void* Cv, int epi,
                                          float scale) {
  char* As = sm;
  char* Bs = sm + 16384;
  int tid = threadIdx.x;
  int wid = tid >> 6, lane = tid & 63;
  int g = lane >> 4, cc = lane & 15;
  int wr = wid >> 1, wc = wid & 1;
  int n0 = blockIdx.x << 7;
  int m0 = blockIdx.y << 7;

  f32x4 acc[4][4];
#pragma unroll
  for (int a = 0; a < 4; ++a)
#pragma unroll
    for (int b = 0; b < 4; ++b)
#pragma unroll
      for (int j = 0; j < 4; ++j) acc[a][b][j] = 0.0f;

  for (int kt = 0; kt < 16; ++kt) {
    int k0 = kt << 6;
#pragma unroll
    for (int it = 0; it < 4; ++it) {
      int L = (it << 12) + (tid << 4);
      int r = L >> 7, o = L & 127;
      int os = swz(r, o);
      gll16(Bt + (size_t)(n0 + r) * 1024 + k0 + (os >> 1),
            Bs + (it << 12) + (wid << 10));
    }
    if constexpr (AF32) {
      const float* A = (const float*)Av;
      int r = tid >> 1, hf = tid & 1;
      const float* src = A + (size_t)(m0 + r) * 1024 + k0 + hf * 32;
      float4 fv[8];
#pragma unroll
      for (int q = 0; q < 8; ++q) fv[q] = ((const float4*)src)[q];
#pragma unroll
      for (int q = 0; q < 4; ++q) {
        float4 a = fv[2 * q], b = fv[2 * q + 1];
        bf16x8 pk;
        pk[0] = (bf16)a.x; pk[1] = (bf16)a.y; pk[2] = (bf16)a.z; pk[3] = (bf16)a.w;
        pk[4] = (bf16)b.x; pk[5] = (bf16)b.y; pk[6] = (bf16)b.z; pk[7] = (bf16)b.w;
        *(bf16x8*)(As + (r << 7) + swz(r, hf * 64 + q * 16)) = pk;
      }
    } else {
      const bf16* A = (const bf16*)Av;
#pragma unroll
      for (int it = 0; it < 4; ++it) {
        int L = (it << 12) + (tid << 4);
        int r = L >> 7, o = L & 127;
        int os = swz(r, o);
        gll16(A + (size_t)(m0 + r) * 1024 + k0 + (os >> 1),
              As + (it << 12) + (wid << 10));
      }
    }
    __syncthreads();
#pragma unroll
    for (int kk = 0; kk < 2; ++kk) {
      bf16x8 af[4], bfr[4];
#pragma unroll
      for (int fm = 0; fm < 4; ++fm) {
        int r = (wr << 6) + (fm << 4) + cc;
        af[fm] = *(const bf16x8*)(As + (r << 7) + swz(r, (kk << 6) + (g << 4)));
      }
#pragma unroll
      for (int fn = 0; fn < 4; ++fn) {
        int r = (wc << 6) + (fn << 4) + cc;
        bfr[fn] = *(const bf16x8*)(Bs + (r << 7) + swz(r, (kk << 6) + (g << 4)));
      }
#pragma unroll
      for (int fm = 0; fm < 4; ++fm)
#pragma unroll
        for (int fn = 0; fn < 4; ++fn)
          acc[fm][fn] = __builtin_amdgcn_mfma_f32_16x16x32_bf16(
              af[fm], bfr[fn], acc[fm][fn], 0, 0, 0);
    }
    __syncthreads();
  }

#pragma unroll
  for (int fm = 0; fm < 4; ++fm) {
#pragma unroll
    for (int fn = 0; fn < 4; ++fn) {
      f32x4 v = acc[fm][fn];
      int mr = m0 + (wr << 6) + (fm << 4) + (g << 2);
      int n = n0 + (wc << 6) + (fn << 4) + cc;
      if (epi == 2) {
        float* C = (float*)Cv;
#pragma unroll
        for (int j = 0; j < 4; ++j) C[(size_t)(mr + j) * 1024 + n] = v[j];
      } else if (epi == 0) {
        bf16* C = (bf16*)Cv;
        int h = n >> 6, e = n & 63;
#pragma unroll
        for (int j = 0; j < 4; ++j) {
          int b = (mr + j) >> 11, s = (mr + j) & 2047;
          C[((size_t)(b * NH + h) * SEQ + s) * HD + e] = (bf16)(v[j] * scale);
        }
      } else {
        bf16* C = (bf16*)Cv;
        int h = n >> 6, e = n & 63;
        int b = mr >> 11, s = mr & 2047;
        bf16x4 t;
#pragma unroll
        for (int j = 0; j < 4; ++j) t[j] = (bf16)v[j];
        *(bf16x4*)(C + ((size_t)(b * NH + h) * HD + e) * SEQ + s) = t;
      }
    }
  }
}

// batched QKV projection, fp32-A path (small workspace)
__global__ __launch_bounds__(256, 2) void gemm_qkv_f32(
    const float* __restrict__ q, const float* __restrict__ k,
    const float* __restrict__ v, const bf16* __restrict__ Wq,
    const bf16* __restrict__ Wk, const bf16* __restrict__ Wv,
    bf16* __restrict__ Qh, bf16* __restrict__ Kh, bf16* __restrict__ Vt,
    float qscale) {
  __shared__ char sm[32768];
  int z = blockIdx.z;
  const void* A = z == 0 ? (const void*)q : z == 1 ? (const void*)k : (const void*)v;
  const bf16* B = z == 0 ? Wq : z == 1 ? Wk : Wv;
  void* C = z == 0 ? (void*)Qh : z == 1 ? (void*)Kh : (void*)Vt;
  gemm_body<true>(sm, A, B, C, z == 2 ? 1 : 0, z == 0 ? qscale : 1.0f);
}

// batched QKV projection, bf16-A path (big workspace)
__global__ __launch_bounds__(256, 2) void gemm_qkv_bf16(
    const bf16* __restrict__ qb, const bf16* __restrict__ kb,
    const bf16* __restrict__ vb, const bf16* __restrict__ Wq,
    const bf16* __restrict__ Wk, const bf16* __restrict__ Wv,
    bf16* __restrict__ Qh, bf16* __restrict__ Kh, bf16* __restrict__ Vt,
    float qscale) {
  __shared__ char sm[32768];
  int z = blockIdx.z;
  const void* A = z == 0 ? (const void*)qb : z == 1 ? (const void*)kb : (const void*)vb;
  const bf16* B = z == 0 ? Wq : z == 1 ? Wk : Wv;
  void* C = z == 0 ? (void*)Qh : z == 1 ? (void*)Kh : (void*)Vt;
  gemm_body<false>(sm, A, B, C, z == 2 ? 1 : 0, z == 0 ? qscale : 1.0f);
}

__global__ __launch_bounds__(256, 2) void gemm_o(const bf16* __restrict__ Att,
                                                 const bf16* __restrict__ Wo,
                                                 float* __restrict__ out) {
  __shared__ char sm[32768];
  gemm_body<false>(sm, Att, Wo, out, 2, 1.0f);
}

// ---------------- flash attention (swapped-QK, in-register softmax) ---------
// Qh: [BH][S][64] bf16 (pre-scaled by 0.125*log2e). Kh: [BH][S][64].
// Vt: [BH][64][S]. Oa: [BH][S][64].
// Grid (16,64): one q-tile per block, heavy tiles first. 4 waves x 32 q-rows.
// KVBLK=64, double-buffered staging, one vmcnt(0)+barrier per tile.
__global__ __launch_bounds__(256, 3) void attn_fwd(const bf16* __restrict__ Qh,
                                                   const bf16* __restrict__ Kh,
                                                   const bf16* __restrict__ Vt,
                                                   bf16* __restrict__ Oa) {
  __shared__ char sm[32768];  // [K0 8K | V0 8K | K1 8K | V1 8K]
  int tid = threadIdx.x, wid = tid >> 6;
  int lane = tid & 63, cc = lane & 31, hi = lane >> 5;
  int h4 = hi << 2;
  int qx = 15 - (int)blockIdx.x;  // heavy first
  int bh = blockIdx.y;
  const bf16* Kb = Kh + (size_t)bh * SEQ * HD;
  const bf16* Vb = Vt + (size_t)bh * HD * SEQ;

  int q0 = qx << 7;
  int sb = q0 + (wid << 5);

  // Q fragments: B-operand col = q-row s = sb+cc, k = kk*16 + hi*8 + 0..7
  const bf16* Qp = Qh + ((size_t)bh * SEQ + sb + cc) * HD + (hi << 3);
  bf16x8 qf[4];
#pragma unroll
  for (int kk = 0; kk < 4; ++kk) qf[kk] = *(const bf16x8*)(Qp + (kk << 4));

  f32x16 acc[2];
#pragma unroll
  for (int eb = 0; eb < 2; ++eb)
#pragma unroll
    for (int r = 0; r < 16; ++r) acc[eb][r] = 0.f;
  float m = -3e38f, l = 0.f;

  int nkv = (qx << 1) + 2;
  int cur = 0;
  // prologue: stage tile 0 into buffer 0
#pragma unroll
  for (int i2 = 0; i2 < 2; ++i2) {
    int L = (i2 << 12) + (tid << 4);
    int r = L >> 7, o = L & 127;
    int os = swz(r, o);
    gll16(Kb + (size_t)r * HD + (os >> 1), sm + (i2 << 12) + (wid << 10));
    gll16(Vb + (size_t)r * SEQ + (os >> 1), sm + 8192 + (i2 << 12) + (wid << 10));
  }
  asm volatile("s_waitcnt vmcnt(0)" ::: "memory");
  __builtin_amdgcn_s_barrier();
  __builtin_amdgcn_sched_barrier(0);

  for (int it = 0; it < nkv; ++it) {
    int t0 = it << 6;
    char* Ks = sm + (cur << 14);
    char* Vs = Ks + 8192;
    // prefetch next tile into other buffer
    if (it + 1 < nkv) {
      char* nb = sm + ((cur ^ 1) << 14);
      int t1 = t0 + 64;
#pragma unroll
      for (int i2 = 0; i2 < 2; ++i2) {
        int L = (i2 << 12) + (tid << 4);
        int r = L >> 7, o = L & 127;
        int os = swz(r, o);
        gll16(Kb + (size_t)(t1 + r) * HD + (os >> 1),
              nb + (i2 << 12) + (wid << 10));
        gll16(Vb + (size_t)r * SEQ + t1 + (os >> 1),
              nb + 8192 + (i2 << 12) + (wid << 10));
      }
    }
    if (t0 <= sb + 31) {
      // S^T = K Q^T : D[t][s], col s = lane&31, row t = tb*32 + crow(r,hi)
      f32x16 sc[2];
      __builtin_amdgcn_s_setprio(1);
#pragma unroll
      for (int tb = 0; tb < 2; ++tb) {
#pragma unroll
        for (int r = 0; r < 16; ++r) sc[tb][r] = 0.f;
#pragma unroll
        for (int kk = 0; kk < 4; ++kk) {
          int rr = (tb << 5) + cc;
          bf16x8 kf = *(const bf16x8*)(Ks + (rr << 7) +
                                       swz(rr, (kk << 5) + (hi << 4)));
          sc[tb] = __builtin_amdgcn_mfma_f32_32x32x16_bf16(kf, qf[kk],
                                                           sc[tb], 0, 0, 0);
        }
      }
      __builtin_amdgcn_s_setprio(0);
      // causal mask (diag tiles only)
      if (t0 + 63 > sb) {
        int s = sb + cc;
#pragma unroll
        for (int tb = 0; tb < 2; ++tb)
#pragma unroll
          for (int r = 0; r < 16; ++r) {
            int t = t0 + (tb << 5) + (r & 3) + ((r >> 2) << 3) + h4;
            if (t > s) sc[tb][r] = -3e38f;
          }
      }
      // row max: full P-row for q-row s=cc lives in lanes {cc, cc+32}
      float pm = sc[0][0];
#pragma unroll
      for (int r = 1; r < 16; ++r) pm = fmaxf(pm, sc[0][r]);
#pragma unroll
      for (int r = 0; r < 16; ++r) pm = fmaxf(pm, sc[1][r]);
      pm = fmaxf(pm, __shfl_xor(pm, 32, 64));
      // defer-max: rescale only when max grew past threshold
      if (!__all(pm - m <= THRD)) {
        float mn = fmaxf(m, pm);
        float sclf = exp2f(m - mn);
        m = mn; l *= sclf;
        int sclb = __builtin_bit_cast(int, sclf);
#pragma unroll
        for (int r = 0; r < 16; ++r) {
          int ssel = (r & 3) + ((r >> 2) << 3) + h4;
          float sr = __builtin_bit_cast(
              float, __builtin_amdgcn_ds_bpermute(ssel << 2, sclb));
          acc[0][r] *= sr;
          acc[1][r] *= sr;
        }
      }
      // P = exp2(sc - m); row sum
      float rs = 0.f;
#pragma unroll
      for (int tb = 0; tb < 2; ++tb)
#pragma unroll
        for (int r = 0; r < 16; ++r) {
          float p = exp2f(sc[tb][r] - m);
          sc[tb][r] = p;
          rs += p;
        }
      l += rs + __shfl_xor(rs, 32, 64);
      // O += P V : build PV A-frags via shfl_xor(32)
#pragma unroll
      for (int ks = 0; ks < 4; ++ks) {
        int tb = ks >> 1, base = (ks & 1) << 3;
        int w00 = pk2(sc[tb][base + 0], sc[tb][base + 1]);
        int w01 = pk2(sc[tb][base + 2], sc[tb][base + 3]);
        int w10 = pk2(sc[tb][base + 4], sc[tb][base + 5]);
        int w11 = pk2(sc[tb][base + 6], sc[tb][base + 7]);
        int selB0 = hi ? w00 : w10;
        int selB1 = hi ? w01 : w11;
        int cross0 = __shfl_xor(selB0, 32, 64);
        int cross1 = __shfl_xor(selB1, 32, 64);
        i32x4 wv;
        wv[0] = hi ? cross0 : w00;
        wv[1] = hi ? cross1 : w01;
        wv[2] = hi ? w10 : cross0;
        wv[3] = hi ? w11 : cross1;
        bf16x8 pa = __builtin_bit_cast(bf16x8, wv);
        __builtin_amdgcn_s_setprio(1);
#pragma unroll
        for (int eb = 0; eb < 2; ++eb) {
          int rr = (eb << 5) + cc;
          bf16x8 vf = *(const bf16x8*)(Vs + (rr << 7) +
                                       swz(rr, (ks << 5) + (hi << 4)));
          acc[eb] = __builtin_amdgcn_mfma_f32_32x32x16_bf16(pa, vf,
                                                            acc[eb], 0, 0, 0);
        }
        __builtin_amdgcn_s_setprio(0);
      }
    }
    asm volatile("s_waitcnt vmcnt(0)" ::: "memory");
    __builtin_amdgcn_s_barrier();
    __builtin_amdgcn_sched_barrier(0);
    cur ^= 1;
  }
  // epilogue: O = acc / l
  float invl = 1.0f / l;
  int ilb = __builtin_bit_cast(int, invl);
  bf16* Op = Oa + ((size_t)bh * SEQ + sb) * HD;
#pragma unroll
  for (int r = 0; r < 16; ++r) {
    int ssel = (r & 3) + ((r >> 2) << 3) + h4;
    float ir = __builtin_bit_cast(
        float, __builtin_amdgcn_ds_bpermute(ssel << 2, ilb));
#pragma unroll
    for (int eb = 0; eb < 2; ++eb)
      Op[(size_t)ssel * HD + (eb << 5) + cc] = (bf16)(acc[eb][r] * ir);
  }
}

// ---------------- launch ----------------
extern "C" void kernel_launch(void* const* d_in, const int* in_sizes, int n_in,
                              void* d_out, int out_size, void* d_ws,
                              size_t ws_size, hipStream_t stream) {
  const float* q = (const float*)d_in[0];
  const float* k = (const float*)d_in[1];
  const float* v = (const float*)d_in[2];
  const float* Wq = (const float*)d_in[3];
  const float* Wk = (const float*)d_in[4];
  const float* Wv = (const float*)d_in[5];
  const float* Wo = (const float*)d_in[6];
  char* ws = (char*)d_ws;

  const size_t MB = 1024 * 1024;
  const float qscale = 0.125f * 1.44269504f;  // 1/sqrt(64) * log2(e)

  bf16* WqT = (bf16*)(ws + 0 * MB);
  bf16* WkT = (bf16*)(ws + 2 * MB);
  bf16* WvT = (bf16*)(ws + 4 * MB);
  bf16* WoT = (bf16*)(ws + 6 * MB);

  conv_wt<<<dim3(16, 16, 4), 256, 0, stream>>>(Wq, Wk, Wv, Wo,
                                               WqT, WkT, WvT, WoT);

  if (ws_size >= 104 * MB) {
    // big path: pre-convert inputs to bf16, pure global_load_lds GEMMs
    bf16* qb = (bf16*)(ws + 8 * MB);
    bf16* kb = (bf16*)(ws + 24 * MB);
    bf16* vb = (bf16*)(ws + 40 * MB);
    bf16* Qh = (bf16*)(ws + 56 * MB);
    bf16* Kh = (bf16*)(ws + 72 * MB);
    bf16* Vt = (bf16*)(ws + 88 * MB);
    bf16* Att = (bf16*)(ws + 8 * MB);  // reuse qb after projections

    conv_in<<<dim3(8192, 3), 256, 0, stream>>>(q, k, v, qb, kb, vb);
    gemm_qkv_bf16<<<dim3(8, 64, 3), 256, 0, stream>>>(
        qb, kb, vb, WqT, WkT, WvT, Qh, Kh, Vt, qscale);
    attn_fwd<<<dim3(16, 64), 256, 0, stream>>>(Qh, Kh, Vt, Att);
    gemm_o<<<dim3(8, 64), 256, 0, stream>>>(Att, WoT, (float*)d_out);
  } else {
    // small path: fp32-A register staging (72 MiB)
    bf16* Qh = (bf16*)(ws + 8 * MB);
    bf16* Kh = (bf16*)(ws + 24 * MB);
    bf16* Vt = (bf16*)(ws + 40 * MB);
    bf16* Att = (bf16*)(ws + 56 * MB);

    gemm_qkv_f32<<<dim3(8, 64, 3), 256, 0, stream>>>(
        q, k, v, WqT, WkT, WvT, Qh, Kh, Vt, qscale);
    attn_fwd<<<dim3(16, 64), 256, 0, stream>>>(Qh, Kh, Vt, Att);
    gemm_o<<<dim3(8, 64), 256, 0, stream>>>(Att, WoT, (float*)d_out);
  }
}

// Round 6
// 222.383 us; speedup vs baseline: 1.9345x; 1.1327x over previous
//
#include <hip/hip_runtime.h>
#include <hip/hip_bf16.h>
#include <stdint.h>

typedef __bf16 bf16;
typedef __bf16 bf16x8 __attribute__((ext_vector_type(8)));
typedef __bf16 bf16x4 __attribute__((ext_vector_type(4)));
typedef __bf16 bf16x2 __attribute__((ext_vector_type(2)));
typedef float f32x4 __attribute__((ext_vector_type(4)));
typedef float f32x16 __attribute__((ext_vector_type(16)));
typedef int i32x4 __attribute__((ext_vector_type(4)));

#define NH   16
#define SEQ  2048
#define DM   1024
#define HD   64
#define THRD 11.0f   // defer-max threshold, log2 domain

// LDS rows are 128 bytes. Swizzle is an involution within a row.
__device__ __forceinline__ int swz(int r, int o) {
  return o ^ ((r & 7) << 4) ^ (((r >> 3) & 1) << 5);
}

__device__ __forceinline__ void gll16(const void* g, void* l) {
  __builtin_amdgcn_global_load_lds(
      (__attribute__((address_space(1))) unsigned int*)(g),
      (__attribute__((address_space(3))) unsigned int*)(l), 16, 0, 0);
}

__device__ __forceinline__ int pk2(float a, float b) {
  bf16x2 t; t[0] = (bf16)a; t[1] = (bf16)b;
  return __builtin_bit_cast(int, t);
}

// ---------------- fused weight transpose-convert ----------------
// z<3:  Wt[h*64+e][d] = (bf16)W[h][d][e]
// z==3: Wt[n][k]      = (bf16)Wo[k][n]
__global__ __launch_bounds__(256) void conv_wt(const float* __restrict__ Wq,
                                               const float* __restrict__ Wk,
                                               const float* __restrict__ Wv,
                                               const float* __restrict__ Wo,
                                               bf16* __restrict__ WqT,
                                               bf16* __restrict__ WkT,
                                               bf16* __restrict__ WvT,
                                               bf16* __restrict__ WoT) {
  __shared__ float tile[64][65];
  int z = blockIdx.z, t = threadIdx.x;
  int d0 = blockIdx.x << 6;
  if (z < 3) {
    const float* W = (z == 0 ? Wq : z == 1 ? Wk : Wv) + ((size_t)blockIdx.y << 16);
#pragma unroll
    for (int i = 0; i < 4; ++i) {
      int slot = (i << 8) + t;
      int r = slot >> 4, c4 = (slot & 15) << 2;
      float4 fv = *(const float4*)(W + (size_t)(d0 + r) * 64 + c4);
      tile[r][c4] = fv.x; tile[r][c4 + 1] = fv.y;
      tile[r][c4 + 2] = fv.z; tile[r][c4 + 3] = fv.w;
    }
  } else {
    int n0 = blockIdx.y << 6;
#pragma unroll
    for (int i = 0; i < 4; ++i) {
      int slot = (i << 8) + t;
      int r = slot >> 4, c4 = (slot & 15) << 2;
      float4 fv = *(const float4*)(Wo + (size_t)(d0 + r) * 1024 + n0 + c4);
      tile[r][c4] = fv.x; tile[r][c4 + 1] = fv.y;
      tile[r][c4 + 2] = fv.z; tile[r][c4 + 3] = fv.w;
    }
  }
  __syncthreads();
  bf16* Wt = z == 0 ? WqT : z == 1 ? WkT : z == 2 ? WvT : WoT;
  size_t base = (z < 3) ? ((size_t)blockIdx.y << 16)
                        : (size_t)(blockIdx.y << 6) * 1024;
  int e = t >> 2, dq = (t & 3) << 4;
  bf16x8 o0, o1;
#pragma unroll
  for (int j = 0; j < 8; ++j) {
    o0[j] = (bf16)tile[dq + j][e];
    o1[j] = (bf16)tile[dq + 8 + j][e];
  }
  bf16* p = Wt + base + (size_t)e * 1024 + d0 + dq;
  *(bf16x8*)p = o0;
  *(bf16x8*)(p + 8) = o1;
}

// ---------------- fp32 -> bf16 flat convert ----------------
__global__ __launch_bounds__(256) void conv_one(const float* __restrict__ src,
                                                bf16* __restrict__ dst) {
  int i = (blockIdx.x * 256 + threadIdx.x) << 2;
  float4 f = *(const float4*)(src + i);
  bf16x4 o; o[0] = (bf16)f.x; o[1] = (bf16)f.y; o[2] = (bf16)f.z; o[3] = (bf16)f.w;
  *(bf16x4*)(dst + i) = o;
}

// ---------------- GEMM: C = A[8192][1024](bf16) * Bt[1024][1024]^T ----------
// epi 0: bf16 -> C[((b*16+h)*2048+s)*64+e] (*scale)  [Q/K projection]
// epi 1: bf16 -> C[((b*16+h)*64+e)*2048+s]           [V projection, transposed]
// epi 2: f32  -> C[mr*1024+n]                        [final Wo GEMM]
__global__ __launch_bounds__(256, 2) void gemm_bt16(const bf16* __restrict__ A,
                                                    const bf16* __restrict__ Bt,
                                                    void* __restrict__ Cv,
                                                    int epi, float scale) {
  __shared__ char sm[32768];
  char* As = sm;
  char* Bs = sm + 16384;
  int tid = threadIdx.x;
  int wid = tid >> 6, lane = tid & 63;
  int g = lane >> 4, cc = lane & 15;
  int wr = wid >> 1, wc = wid & 1;
  int n0 = blockIdx.x << 7;
  int m0 = blockIdx.y << 7;

  f32x4 acc[4][4];
#pragma unroll
  for (int a = 0; a < 4; ++a)
#pragma unroll
    for (int b = 0; b < 4; ++b)
#pragma unroll
      for (int j = 0; j < 4; ++j) acc[a][b][j] = 0.0f;

  for (int kt = 0; kt < 16; ++kt) {
    int k0 = kt << 6;
#pragma unroll
    for (int it = 0; it < 4; ++it) {
      int L = (it << 12) + (tid << 4);
      int r = L >> 7, o = L & 127;
      int os = swz(r, o);
      gll16(Bt + (size_t)(n0 + r) * 1024 + k0 + (os >> 1),
            Bs + (it << 12) + (wid << 10));
      gll16(A + (size_t)(m0 + r) * 1024 + k0 + (os >> 1),
            As + (it << 12) + (wid << 10));
    }
    __syncthreads();
#pragma unroll
    for (int kk = 0; kk < 2; ++kk) {
      bf16x8 af[4], bfr[4];
#pragma unroll
      for (int fm = 0; fm < 4; ++fm) {
        int r = (wr << 6) + (fm << 4) + cc;
        af[fm] = *(const bf16x8*)(As + (r << 7) + swz(r, (kk << 6) + (g << 4)));
      }
#pragma unroll
      for (int fn = 0; fn < 4; ++fn) {
        int r = (wc << 6) + (fn << 4) + cc;
        bfr[fn] = *(const bf16x8*)(Bs + (r << 7) + swz(r, (kk << 6) + (g << 4)));
      }
#pragma unroll
      for (int fm = 0; fm < 4; ++fm)
#pragma unroll
        for (int fn = 0; fn < 4; ++fn)
          acc[fm][fn] = __builtin_amdgcn_mfma_f32_16x16x32_bf16(
              af[fm], bfr[fn], acc[fm][fn], 0, 0, 0);
    }
    __syncthreads();
  }

#pragma unroll
  for (int fm = 0; fm < 4; ++fm) {
#pragma unroll
    for (int fn = 0; fn < 4; ++fn) {
      f32x4 v = acc[fm][fn];
      int mr = m0 + (wr << 6) + (fm << 4) + (g << 2);
      int n = n0 + (wc << 6) + (fn << 4) + cc;
      if (epi == 2) {
        float* C = (float*)Cv;
#pragma unroll
        for (int j = 0; j < 4; ++j) C[(size_t)(mr + j) * 1024 + n] = v[j];
      } else if (epi == 0) {
        bf16* C = (bf16*)Cv;
        int h = n >> 6, e = n & 63;
#pragma unroll
        for (int j = 0; j < 4; ++j) {
          int b = (mr + j) >> 11, s = (mr + j) & 2047;
          C[((size_t)(b * NH + h) * SEQ + s) * HD + e] = (bf16)(v[j] * scale);
        }
      } else {
        bf16* C = (bf16*)Cv;
        int h = n >> 6, e = n & 63;
        int b = mr >> 11, s = mr & 2047;
        bf16x4 t;
#pragma unroll
        for (int j = 0; j < 4; ++j) t[j] = (bf16)v[j];
        *(bf16x4*)(C + ((size_t)(b * NH + h) * HD + e) * SEQ + s) = t;
      }
    }
  }
}

// ---------------- flash attention (swapped-QK, in-register softmax) ---------
// Qh: [BH][S][64] bf16 (pre-scaled by 0.125*log2e). Kh: [BH][S][64].
// Vt: [BH][64][S]. Oa: [BH][S][64].
// Grid (8,64): paired q-tiles (qp, 15-qp) -> uniform 34 KV-iters per block.
// 4 waves x 32 q-rows. KVBLK=64, double-buffered, one vmcnt(0)+barrier/tile.
__global__ __launch_bounds__(256, 3) void attn_fwd(const bf16* __restrict__ Qh,
                                                   const bf16* __restrict__ Kh,
                                                   const bf16* __restrict__ Vt,
                                                   bf16* __restrict__ Oa) {
  __shared__ char sm[32768];  // [K0 8K | V0 8K | K1 8K | V1 8K]
  int tid = threadIdx.x, wid = tid >> 6;
  int lane = tid & 63, cc = lane & 31, hi = lane >> 5;
  int h4 = hi << 2;
  int qp = blockIdx.x, bh = blockIdx.y;
  const bf16* Kb = Kh + (size_t)bh * SEQ * HD;
  const bf16* Vb = Vt + (size_t)bh * HD * SEQ;

  for (int ph = 0; ph < 2; ++ph) {
    int qx = ph ? (15 - qp) : qp;
    int q0 = qx << 7;
    int sb = q0 + (wid << 5);

    // Q fragments: B-operand col = q-row s = sb+cc, k = kk*16 + hi*8 + 0..7
    const bf16* Qp = Qh + ((size_t)bh * SEQ + sb + cc) * HD + (hi << 3);
    bf16x8 qf[4];
#pragma unroll
    for (int kk = 0; kk < 4; ++kk) qf[kk] = *(const bf16x8*)(Qp + (kk << 4));

    f32x16 acc[2];
#pragma unroll
    for (int eb = 0; eb < 2; ++eb)
#pragma unroll
      for (int r = 0; r < 16; ++r) acc[eb][r] = 0.f;
    float m = -3e38f, l = 0.f;

    int nkv = (qx << 1) + 2;
    int cur = 0;
    // prologue: stage tile 0 into buffer 0
#pragma unroll
    for (int i2 = 0; i2 < 2; ++i2) {
      int L = (i2 << 12) + (tid << 4);
      int r = L >> 7, o = L & 127;
      int os = swz(r, o);
      gll16(Kb + (size_t)r * HD + (os >> 1), sm + (i2 << 12) + (wid << 10));
      gll16(Vb + (size_t)r * SEQ + (os >> 1), sm + 8192 + (i2 << 12) + (wid << 10));
    }
    asm volatile("s_waitcnt vmcnt(0)" ::: "memory");
    __builtin_amdgcn_s_barrier();
    __builtin_amdgcn_sched_barrier(0);

    for (int it = 0; it < nkv; ++it) {
      int t0 = it << 6;
      char* Ks = sm + (cur << 14);
      char* Vs = Ks + 8192;
      // prefetch next tile into other buffer
      if (it + 1 < nkv) {
        char* nb = sm + ((cur ^ 1) << 14);
        int t1 = t0 + 64;
#pragma unroll
        for (int i2 = 0; i2 < 2; ++i2) {
          int L = (i2 << 12) + (tid << 4);
          int r = L >> 7, o = L & 127;
          int os = swz(r, o);
          gll16(Kb + (size_t)(t1 + r) * HD + (os >> 1),
                nb + (i2 << 12) + (wid << 10));
          gll16(Vb + (size_t)r * SEQ + t1 + (os >> 1),
                nb + 8192 + (i2 << 12) + (wid << 10));
        }
      }
      if (t0 <= sb + 31) {
        // S^T = K Q^T : D[t][s], col s = lane&31, row t = tb*32 + crow(r,hi)
        f32x16 sc[2];
#pragma unroll
        for (int tb = 0; tb < 2; ++tb) {
#pragma unroll
          for (int r = 0; r < 16; ++r) sc[tb][r] = 0.f;
#pragma unroll
          for (int kk = 0; kk < 4; ++kk) {
            int rr = (tb << 5) + cc;
            bf16x8 kf = *(const bf16x8*)(Ks + (rr << 7) +
                                         swz(rr, (kk << 5) + (hi << 4)));
            sc[tb] = __builtin_amdgcn_mfma_f32_32x32x16_bf16(kf, qf[kk],
                                                             sc[tb], 0, 0, 0);
          }
        }
        // causal mask (diag tiles only)
        if (t0 + 63 > sb) {
          int s = sb + cc;
#pragma unroll
          for (int tb = 0; tb < 2; ++tb)
#pragma unroll
            for (int r = 0; r < 16; ++r) {
              int t = t0 + (tb << 5) + (r & 3) + ((r >> 2) << 3) + h4;
              if (t > s) sc[tb][r] = -3e38f;
            }
        }
        // row max (tree: depth 5 instead of serial-31)
        float tm[16];
#pragma unroll
        for (int r = 0; r < 16; ++r) tm[r] = fmaxf(sc[0][r], sc[1][r]);
#pragma unroll
        for (int s2 = 8; s2 >= 1; s2 >>= 1)
#pragma unroll
          for (int r = 0; r < 8; ++r)
            if (r < s2) tm[r] = fmaxf(tm[r], tm[r + s2]);
        float pm = fmaxf(tm[0], __shfl_xor(tm[0], 32, 64));
        // defer-max: rescale only when max grew past threshold
        if (!__all(pm - m <= THRD)) {
          float mn = fmaxf(m, pm);
          float sclf = exp2f(m - mn);
          m = mn; l *= sclf;
          int sclb = __builtin_bit_cast(int, sclf);
#pragma unroll
          for (int r = 0; r < 16; ++r) {
            int ssel = (r & 3) + ((r >> 2) << 3) + h4;
            float sr = __builtin_bit_cast(
                float, __builtin_amdgcn_ds_bpermute(ssel << 2, sclb));
            acc[0][r] *= sr;
            acc[1][r] *= sr;
          }
        }
        // P = exp2(sc - m); row sum (pairwise tree)
        float ts[16];
#pragma unroll
        for (int r = 0; r < 16; ++r) {
          float p0 = exp2f(sc[0][r] - m);
          float p1 = exp2f(sc[1][r] - m);
          sc[0][r] = p0; sc[1][r] = p1;
          ts[r] = p0 + p1;
        }
#pragma unroll
        for (int s2 = 8; s2 >= 1; s2 >>= 1)
#pragma unroll
          for (int r = 0; r < 8; ++r)
            if (r < s2) ts[r] += ts[r + s2];
        l += ts[0] + __shfl_xor(ts[0], 32, 64);
        // O += P V : build PV A-frags via shfl_xor(32)
#pragma unroll
        for (int ks = 0; ks < 4; ++ks) {
          int tb = ks >> 1, base = (ks & 1) << 3;
          int w00 = pk2(sc[tb][base + 0], sc[tb][base + 1]);
          int w01 = pk2(sc[tb][base + 2], sc[tb][base + 3]);
          int w10 = pk2(sc[tb][base + 4], sc[tb][base + 5]);
          int w11 = pk2(sc[tb][base + 6], sc[tb][base + 7]);
          int selB0 = hi ? w00 : w10;
          int selB1 = hi ? w01 : w11;
          int cross0 = __shfl_xor(selB0, 32, 64);
          int cross1 = __shfl_xor(selB1, 32, 64);
          i32x4 wv;
          wv[0] = hi ? cross0 : w00;
          wv[1] = hi ? cross1 : w01;
          wv[2] = hi ? w10 : cross0;
          wv[3] = hi ? w11 : cross1;
          bf16x8 pa = __builtin_bit_cast(bf16x8, wv);
#pragma unroll
          for (int eb = 0; eb < 2; ++eb) {
            int rr = (eb << 5) + cc;
            bf16x8 vf = *(const bf16x8*)(Vs + (rr << 7) +
                                         swz(rr, (ks << 5) + (hi << 4)));
            acc[eb] = __builtin_amdgcn_mfma_f32_32x32x16_bf16(pa, vf,
                                                              acc[eb], 0, 0, 0);
          }
        }
      }
      asm volatile("s_waitcnt vmcnt(0)" ::: "memory");
      __builtin_amdgcn_s_barrier();
      __builtin_amdgcn_sched_barrier(0);
      cur ^= 1;
    }
    // epilogue: O = acc / l
    float invl = 1.0f / l;
    int ilb = __builtin_bit_cast(int, invl);
    bf16* Op = Oa + ((size_t)bh * SEQ + sb) * HD;
#pragma unroll
    for (int r = 0; r < 16; ++r) {
      int ssel = (r & 3) + ((r >> 2) << 3) + h4;
      float ir = __builtin_bit_cast(
          float, __builtin_amdgcn_ds_bpermute(ssel << 2, ilb));
#pragma unroll
      for (int eb = 0; eb < 2; ++eb)
        Op[(size_t)ssel * HD + (eb << 5) + cc] = (bf16)(acc[eb][r] * ir);
    }
  }
}

// ---------------- launch ----------------
extern "C" void kernel_launch(void* const* d_in, const int* in_sizes, int n_in,
                              void* d_out, int out_size, void* d_ws,
                              size_t ws_size, hipStream_t stream) {
  const float* q = (const float*)d_in[0];
  const float* k = (const float*)d_in[1];
  const float* v = (const float*)d_in[2];
  const float* Wq = (const float*)d_in[3];
  const float* Wk = (const float*)d_in[4];
  const float* Wv = (const float*)d_in[5];
  const float* Wo = (const float*)d_in[6];
  char* ws = (char*)d_ws;

  const size_t MB = 1024 * 1024;
  const float qscale = 0.125f * 1.44269504f;  // 1/sqrt(64) * log2(e)

  bf16* WqT = (bf16*)(ws + 0 * MB);
  bf16* WkT = (bf16*)(ws + 2 * MB);
  bf16* WvT = (bf16*)(ws + 4 * MB);
  bf16* WoT = (bf16*)(ws + 6 * MB);
  bf16* tmp = (bf16*)(ws + 8 * MB);   // bf16 input scratch, later Att
  bf16* Qh  = (bf16*)(ws + 24 * MB);
  bf16* Kh  = (bf16*)(ws + 40 * MB);
  bf16* Vt  = (bf16*)(ws + 56 * MB);
  bf16* Att = tmp;                    // reuse after projections (72 MiB total)

  conv_wt<<<dim3(16, 16, 4), 256, 0, stream>>>(Wq, Wk, Wv, Wo,
                                               WqT, WkT, WvT, WoT);

  dim3 gg(8, 64);
  conv_one<<<8192, 256, 0, stream>>>(q, tmp);
  gemm_bt16<<<gg, 256, 0, stream>>>(tmp, WqT, Qh, 0, qscale);
  conv_one<<<8192, 256, 0, stream>>>(k, tmp);
  gemm_bt16<<<gg, 256, 0, stream>>>(tmp, WkT, Kh, 0, 1.0f);
  conv_one<<<8192, 256, 0, stream>>>(v, tmp);
  gemm_bt16<<<gg, 256, 0, stream>>>(tmp, WvT, Vt, 1, 1.0f);

  attn_fwd<<<dim3(8, 64), 256, 0, stream>>>(Qh, Kh, Vt, Att);

  gemm_bt16<<<gg, 256, 0, stream>>>(Att, WoT, (float*)d_out, 2, 1.0f);
}